// Round 6
// baseline (315.922 us; speedup 1.0000x reference)
//
#include <hip/hip_runtime.h>
#include <math.h>

// Problem constants
#define B_    4
#define LQ_   1024
#define LKV_  4096
#define DM    512    // model dim
#define NH    4
#define HD_   128    // head dim

typedef _Float16 half8   __attribute__((ext_vector_type(8)));
typedef _Float16 half4_t __attribute__((ext_vector_type(4)));
typedef float    floatx4 __attribute__((ext_vector_type(4)));

#define MFMA16(a, b, c) __builtin_amdgcn_mfma_f32_16x16x32_f16((a), (b), (c), 0, 0, 0)

// ---------------------------------------------------------------------------
// prep: cast x, enc, and the 4 weight matrices to f16 in one pass.
// float4 index space: x 524288 | enc 2097152 | W 4x65536  => 2,883,584 total
// ---------------------------------------------------------------------------
__global__ __launch_bounds__(256) void prep_cast(
    const float* __restrict__ x, const float* __restrict__ enc,
    const float* __restrict__ Wq, const float* __restrict__ Wk,
    const float* __restrict__ Wv, const float* __restrict__ Wo,
    _Float16* __restrict__ xh, _Float16* __restrict__ ench,
    _Float16* __restrict__ Wh)
{
  int i = blockIdx.x * 256 + threadIdx.x;
  const float* src; _Float16* dst; size_t off;
  if (i < 524288) { src = x; dst = xh; off = i; }
  else if (i < 2621440) { src = enc; dst = ench; off = i - 524288; }
  else {
    int j = i - 2621440;            // 0..262143
    int wsel = j >> 16;             // 65536 float4 per W
    src = (wsel == 0) ? Wq : (wsel == 1) ? Wk : (wsel == 2) ? Wv : Wo;
    dst = Wh + ((size_t)wsel << 18);
    off = j & 65535;
  }
  float4 v = *(const float4*)(src + off * 4);
  half4_t h;
  h[0] = (_Float16)v.x; h[1] = (_Float16)v.y;
  h[2] = (_Float16)v.z; h[3] = (_Float16)v.w;
  *(half4_t*)(dst + off * 4) = h;
}

// ---------------------------------------------------------------------------
// f16 MFMA GEMM: Y[M,512] = (X @ W^T + bias) * scale. All-f16 inputs.
// MODE 0: f32 out. MODE 1: f16 out.
// Block 256 = 4 waves (2x2 of 64x64), tile 128x128, BK=64.
// A-frag: A[m=lane&15][k=quad*8+j]; B-frag: B[k=quad*8+j][n=lane&15]
// C/D:    row=quad*4+reg, col=lane&15
// ---------------------------------------------------------------------------
template<int MODE>
__global__ __launch_bounds__(256) void proj_mfma(
    const _Float16* __restrict__ X,
    const _Float16* __restrict__ W,
    const float* __restrict__ bias,
    void* __restrict__ Yv, float scale)
{
  __shared__ _Float16 Xs[128][72];
  __shared__ _Float16 Ws[128][72];

  const int tid  = threadIdx.x;
  const int lane = tid & 63;
  const int w    = tid >> 6;
  const int n16  = lane & 15;
  const int quad = lane >> 4;
  const int wm   = (w & 1) * 64;
  const int wn   = (w >> 1) * 64;
  const int row0 = blockIdx.x * 128;
  const int col0 = blockIdx.y * 128;

  floatx4 acc[4][4];
#pragma unroll
  for (int a = 0; a < 4; ++a)
#pragma unroll
    for (int b = 0; b < 4; ++b) acc[a][b] = (floatx4){0.f, 0.f, 0.f, 0.f};

  for (int k0 = 0; k0 < 512; k0 += 64) {
#pragma unroll
    for (int i = 0; i < 4; ++i) {
      int c = i * 256 + tid;
      int r = c >> 3, off = (c & 7) * 8;
      *(half8*)&Xs[r][off] = *(const half8*)(X + (size_t)(row0 + r) * 512 + k0 + off);
      *(half8*)&Ws[r][off] = *(const half8*)(W + (size_t)(col0 + r) * 512 + k0 + off);
    }
    __syncthreads();
#pragma unroll
    for (int kc = 0; kc < 2; ++kc) {
      half8 af[4], bf[4];
#pragma unroll
      for (int mb = 0; mb < 4; ++mb)
        af[mb] = *(const half8*)&Xs[wm + mb * 16 + n16][kc * 32 + quad * 8];
#pragma unroll
      for (int nb = 0; nb < 4; ++nb)
        bf[nb] = *(const half8*)&Ws[wn + nb * 16 + n16][kc * 32 + quad * 8];
#pragma unroll
      for (int mb = 0; mb < 4; ++mb)
#pragma unroll
        for (int nb = 0; nb < 4; ++nb)
          acc[mb][nb] = MFMA16(af[mb], bf[nb], acc[mb][nb]);
    }
    __syncthreads();
  }

#pragma unroll
  for (int mb = 0; mb < 4; ++mb) {
#pragma unroll
    for (int nb = 0; nb < 4; ++nb) {
#pragma unroll
      for (int r = 0; r < 4; ++r) {
        int row = row0 + wm + mb * 16 + quad * 4 + r;
        int col = col0 + wn + nb * 16 + n16;
        float v = (acc[mb][nb][r] + bias[col]) * scale;
        if (MODE == 0) ((float*)Yv)[(size_t)row * 512 + col] = v;
        else ((_Float16*)Yv)[(size_t)row * 512 + col] = (_Float16)v;
      }
    }
  }
}

// ---------------------------------------------------------------------------
// Fused K+V projection: stages the enc tile once, computes K (row-major f16)
// and V (transposed per-head to Vt[(b*4+coly)*128+d][LKV]).
// ---------------------------------------------------------------------------
__global__ __launch_bounds__(256, 2) void proj_kv(
    const _Float16* __restrict__ Xe,     // ench [B*LKV, 512]
    const _Float16* __restrict__ Wk,
    const _Float16* __restrict__ Wv,
    const float* __restrict__ bk,
    const float* __restrict__ bv,
    _Float16* __restrict__ Kh,
    _Float16* __restrict__ Vt)
{
  __shared__ _Float16 SM[3 * 128 * 72];          // 55,296 B
  _Float16 (*Xs)[72]  = (_Float16(*)[72])SM;
  _Float16 (*Wks)[72] = (_Float16(*)[72])(SM + 128 * 72);
  _Float16 (*Wvs)[72] = (_Float16(*)[72])(SM + 2 * 128 * 72);

  const int tid  = threadIdx.x;
  const int lane = tid & 63;
  const int w    = tid >> 6;
  const int n16  = lane & 15;
  const int quad = lane >> 4;
  const int wm   = (w & 1) * 64;
  const int wn   = (w >> 1) * 64;
  const int row0 = blockIdx.x * 128;             // enc row (kv)
  const int col0 = blockIdx.y * 128;             // output col (d)

  floatx4 accK[4][4], accV[4][4];
#pragma unroll
  for (int a = 0; a < 4; ++a)
#pragma unroll
    for (int b = 0; b < 4; ++b) {
      accK[a][b] = (floatx4){0.f, 0.f, 0.f, 0.f};
      accV[a][b] = (floatx4){0.f, 0.f, 0.f, 0.f};
    }

  for (int k0 = 0; k0 < 512; k0 += 64) {
#pragma unroll
    for (int i = 0; i < 4; ++i) {
      int c = i * 256 + tid;
      int r = c >> 3, off = (c & 7) * 8;
      *(half8*)&Xs[r][off]  = *(const half8*)(Xe + (size_t)(row0 + r) * 512 + k0 + off);
      *(half8*)&Wks[r][off] = *(const half8*)(Wk + (size_t)(col0 + r) * 512 + k0 + off);
      *(half8*)&Wvs[r][off] = *(const half8*)(Wv + (size_t)(col0 + r) * 512 + k0 + off);
    }
    __syncthreads();
#pragma unroll
    for (int kc = 0; kc < 2; ++kc) {
      half8 af[4], bkf[4], bvf[4];
#pragma unroll
      for (int mb = 0; mb < 4; ++mb)
        af[mb] = *(const half8*)&Xs[wm + mb * 16 + n16][kc * 32 + quad * 8];
#pragma unroll
      for (int nb = 0; nb < 4; ++nb) {
        bkf[nb] = *(const half8*)&Wks[wn + nb * 16 + n16][kc * 32 + quad * 8];
        bvf[nb] = *(const half8*)&Wvs[wn + nb * 16 + n16][kc * 32 + quad * 8];
      }
#pragma unroll
      for (int mb = 0; mb < 4; ++mb)
#pragma unroll
        for (int nb = 0; nb < 4; ++nb) {
          accK[mb][nb] = MFMA16(af[mb], bkf[nb], accK[mb][nb]);
          accV[mb][nb] = MFMA16(af[mb], bvf[nb], accV[mb][nb]);
        }
    }
    __syncthreads();
  }

  // K epilogue: row-major f16
#pragma unroll
  for (int mb = 0; mb < 4; ++mb) {
#pragma unroll
    for (int nb = 0; nb < 4; ++nb) {
#pragma unroll
      for (int r = 0; r < 4; ++r) {
        int row = row0 + wm + mb * 16 + quad * 4 + r;
        int col = col0 + wn + nb * 16 + n16;
        Kh[(size_t)row * 512 + col] = (_Float16)(accK[mb][nb][r] + bk[col]);
      }
    }
  }

  // V epilogue: transpose through LDS. acc rows = kv, cols = d.
  _Float16 (*Ts)[144] = (_Float16(*)[144])SM;    // 128 x 144 fits in SM
#pragma unroll
  for (int mb = 0; mb < 4; ++mb) {
#pragma unroll
    for (int nb = 0; nb < 4; ++nb) {
      int dl = wn + nb * 16 + n16;
      float bi = bv[col0 + dl];
      half4_t hv;
#pragma unroll
      for (int r = 0; r < 4; ++r) hv[r] = (_Float16)(accV[mb][nb][r] + bi);
      *(half4_t*)&Ts[dl][wm + mb * 16 + quad * 4] = hv;
    }
  }
  __syncthreads();
  int b   = row0 >> 12;
  int kv0 = row0 & 4095;
#pragma unroll
  for (int i = 0; i < 8; ++i) {
    int f = i * 256 + tid;
    int dl = f >> 4, kv8 = (f & 15) * 8;
    half8 ov = *(const half8*)&Ts[dl][kv8];
    *(half8*)(Vt + (size_t)((b * 4 + blockIdx.y) * 128 + dl) * LKV_ + kv0 + kv8) = ov;
  }
}

// ---------------------------------------------------------------------------
// Flash attention, S^T form, split-KV x8. Block = 4 waves x 32 q = 128 q.
// P buffer ALIASES the K-tile LDS (P is per-wave-private; extra barrier
// after S-MFMAs protects cross-wave K reads). LDS 36 KB -> 4 blocks/CU.
// ---------------------------------------------------------------------------
__global__ __launch_bounds__(256, 4) void flash_mfma2(
    const _Float16* __restrict__ Qh,   // [B*LQ, 512], pre-scaled
    const _Float16* __restrict__ Kh,   // [B*LKV, 512]
    const _Float16* __restrict__ Vtg,  // [B*NH*HD, LKV], d-major
    _Float16* __restrict__ Opart,      // [128][1024][128] f16 unnormalized
    float* __restrict__ ml)            // [128][1024][2]
{
  __shared__ _Float16 U[4 * 32 * 72];  // 18,432 B: K tiles (64x136=8704) | P (4x32x72)
  __shared__ _Float16 Vs[128][72];     // 18,432 B: V tile, d-major
  _Float16 (*Ks)[136] = (_Float16(*)[136])U;
  _Float16* Ps = U;                    // [4][32][72] alias

  const int tid  = threadIdx.x;
  const int lane = tid & 63;
  const int w    = tid >> 6;
  const int n16  = lane & 15;
  const int quad = lane >> 4;

  const int xb    = blockIdx.x;        // bh*8 + split  (128)
  const int qt    = blockIdx.y;        // 0..7, 128 q each
  const int split = xb & 7;
  const int bh    = xb >> 3;
  const int h = bh & 3, b = bh >> 2;

  const _Float16* Qg = Qh + (size_t)(b * LQ_ + qt * 128) * DM + h * HD_;
  const _Float16* Kg = Kh + (size_t)(b * LKV_) * DM + h * HD_;
  const _Float16* Vg = Vtg + (size_t)(bh * HD_) * LKV_;

  // load Q frags for this wave (q = w*32 + qb*16 + n16) via 2 chunks through Ks
  half8 qf[2][4];
  const int chunk = w >> 1;
  const int qrb   = (w & 1) * 32;
#pragma unroll
  for (int c = 0; c < 2; ++c) {
#pragma unroll
    for (int i = 0; i < 4; ++i) {
      int f = i * 256 + tid;
      int r = f >> 4, c8 = (f & 15) * 8;
      *(half8*)&Ks[r][c8] = *(const half8*)(Qg + (size_t)(c * 64 + r) * DM + c8);
    }
    __syncthreads();
    if (chunk == c) {
#pragma unroll
      for (int qb = 0; qb < 2; ++qb)
#pragma unroll
        for (int kc = 0; kc < 4; ++kc)
          qf[qb][kc] = *(const half8*)&Ks[qrb + qb * 16 + n16][kc * 32 + quad * 8];
    }
    __syncthreads();
  }

  floatx4 o[2][8];
#pragma unroll
  for (int mb = 0; mb < 2; ++mb)
#pragma unroll
    for (int vb = 0; vb < 8; ++vb) o[mb][vb] = (floatx4){0.f, 0.f, 0.f, 0.f};
  float m_i[2] = {-INFINITY, -INFINITY};
  float l_i[2] = {0.f, 0.f};

  for (int kt = split * 8; kt < split * 8 + 8; ++kt) {
    // stage K (64 kv x 128 d) and V (128 d x 64 kv)
#pragma unroll
    for (int i = 0; i < 4; ++i) {
      int f = i * 256 + tid;
      int r = f >> 4, c8 = (f & 15) * 8;
      *(half8*)&Ks[r][c8] = *(const half8*)(Kg + (size_t)(kt * 64 + r) * DM + c8);
    }
#pragma unroll
    for (int i = 0; i < 4; ++i) {
      int f = i * 256 + tid;
      int d = f >> 3, kv8 = (f & 7) * 8;
      *(half8*)&Vs[d][kv8] = *(const half8*)(Vg + (size_t)d * LKV_ + kt * 64 + kv8);
    }
    __syncthreads();

    // S^T per wave: rows kv=cb*16+quad*4+r, col q=qb*16+n16
    floatx4 s[2][4];
#pragma unroll
    for (int qb = 0; qb < 2; ++qb)
#pragma unroll
      for (int cb = 0; cb < 4; ++cb) s[qb][cb] = (floatx4){0.f, 0.f, 0.f, 0.f};
#pragma unroll
    for (int cb = 0; cb < 4; ++cb) {
#pragma unroll
      for (int kc = 0; kc < 4; ++kc) {
        half8 kf = *(const half8*)&Ks[cb * 16 + n16][kc * 32 + quad * 8];
        s[0][cb] = MFMA16(kf, qf[0][kc], s[0][cb]);
        s[1][cb] = MFMA16(kf, qf[1][kc], s[1][cb]);
      }
    }
    __syncthreads();   // all waves done reading Ks before P (aliased) overwrites

    // online softmax per q column; reduce across quads (xor 16, 32)
    float alpha[2];
#pragma unroll
    for (int qb = 0; qb < 2; ++qb) {
      float mx = -INFINITY;
#pragma unroll
      for (int cb = 0; cb < 4; ++cb)
#pragma unroll
        for (int r = 0; r < 4; ++r) mx = fmaxf(mx, s[qb][cb][r]);
      mx = fmaxf(mx, __shfl_xor(mx, 16));
      mx = fmaxf(mx, __shfl_xor(mx, 32));
      float mn = fmaxf(m_i[qb], mx);
      alpha[qb] = __expf(m_i[qb] - mn);
      m_i[qb] = mn;
      float rs = 0.f;
#pragma unroll
      for (int cb = 0; cb < 4; ++cb) {
        half4_t ph;
#pragma unroll
        for (int r = 0; r < 4; ++r) {
          float p = __expf(s[qb][cb][r] - mn);
          rs += p;
          ph[r] = (_Float16)p;
        }
        *(half4_t*)&Ps[(w * 32 + qb * 16 + n16) * 72 + cb * 16 + quad * 4] = ph;
      }
      rs += __shfl_xor(rs, 16);
      rs += __shfl_xor(rs, 32);
      l_i[qb] = l_i[qb] * alpha[qb] + rs;
    }

    // rescale O: row q = mb*16 + quad*4 + r -> alpha from lane n16=quad*4+r
#pragma unroll
    for (int mb = 0; mb < 2; ++mb) {
#pragma unroll
      for (int r = 0; r < 4; ++r) {
        float a = __shfl(alpha[mb], (lane & 48) | (quad * 4 + r));
#pragma unroll
        for (int vb = 0; vb < 8; ++vb) o[mb][vb][r] *= a;
      }
    }

    // O += P V  (P from per-wave LDS slice; intra-wave ordering)
    half8 pf[2][2];
#pragma unroll
    for (int mb = 0; mb < 2; ++mb)
#pragma unroll
      for (int kc = 0; kc < 2; ++kc)
        pf[mb][kc] = *(const half8*)&Ps[(w * 32 + mb * 16 + n16) * 72 + kc * 32 + quad * 8];
#pragma unroll
    for (int vb = 0; vb < 8; ++vb) {
#pragma unroll
      for (int kc = 0; kc < 2; ++kc) {
        half8 vf = *(const half8*)&Vs[vb * 16 + n16][kc * 32 + quad * 8];
        o[0][vb] = MFMA16(pf[0][kc], vf, o[0][vb]);
        o[1][vb] = MFMA16(pf[1][kc], vf, o[1][vb]);
      }
    }
    __syncthreads();   // P (and Vs) free before next stage
  }

  // write unnormalized partial O (f16) and (m,l)
  _Float16* Og = Opart + ((size_t)xb * 1024 + qt * 128 + w * 32) * HD_;
#pragma unroll
  for (int mb = 0; mb < 2; ++mb) {
#pragma unroll
    for (int r = 0; r < 4; ++r) {
#pragma unroll
      for (int vb = 0; vb < 8; ++vb)
        Og[(size_t)(mb * 16 + quad * 4 + r) * HD_ + vb * 16 + n16] =
            (_Float16)o[mb][vb][r];
    }
  }
  if (quad == 0) {
#pragma unroll
    for (int qb = 0; qb < 2; ++qb) {
      size_t qi = (size_t)xb * 1024 + qt * 128 + w * 32 + qb * 16 + n16;
      ml[qi * 2] = m_i[qb];
      ml[qi * 2 + 1] = l_i[qb];
    }
  }
}

// ---------------------------------------------------------------------------
// Combine 8 KV-split partials -> CTXh f16 [B*LQ, 512]
// ---------------------------------------------------------------------------
__global__ __launch_bounds__(256) void combine_splits(
    const _Float16* __restrict__ Opart,
    const float* __restrict__ ml,
    _Float16* __restrict__ CTXh)
{
  int g  = blockIdx.x * 2 + (threadIdx.x >> 7);   // row 0..16383 (bh*1024+q)
  int d  = threadIdx.x & 127;
  int bh = g >> 10, q = g & 1023;
  int b = bh >> 2, h = bh & 3;

  float m[8], l[8], M = -INFINITY;
#pragma unroll
  for (int p = 0; p < 8; ++p) {
    size_t idx = ((size_t)(bh * 8 + p) * 1024 + q) * 2;
    m[p] = ml[idx]; l[p] = ml[idx + 1];
    M = fmaxf(M, m[p]);
  }
  float L = 0.f, o = 0.f;
#pragma unroll
  for (int p = 0; p < 8; ++p) {
    float wgt = __expf(m[p] - M);
    L += wgt * l[p];
    o += wgt * (float)Opart[((size_t)(bh * 8 + p) * 1024 + q) * HD_ + d];
  }
  CTXh[(size_t)(b * LQ_ + q) * DM + h * HD_ + d] = (_Float16)(o / L);
}

// ---------------------------------------------------------------------------
extern "C" void kernel_launch(void* const* d_in, const int* in_sizes, int n_in,
                              void* d_out, int out_size, void* d_ws, size_t ws_size,
                              hipStream_t stream) {
  const float* x   = (const float*)d_in[0];
  const float* enc = (const float*)d_in[1];
  const float* Wq  = (const float*)d_in[2];
  const float* Wk  = (const float*)d_in[3];
  const float* Wv  = (const float*)d_in[4];
  const float* bq  = (const float*)d_in[5];
  const float* bk  = (const float*)d_in[6];
  const float* bv  = (const float*)d_in[7];
  const float* Wo  = (const float*)d_in[8];
  const float* bo  = (const float*)d_in[9];
  float* out = (float*)d_out;

  // workspace layout (MB offsets):
  //   0  Qh    f16 [4096 x 512]         4 MB
  //   4  Kh    f16 [16384 x 512]       16 MB
  //  20  Vtg   f16 [2048 x 4096]       16 MB
  //  36  ench  f16 [16384 x 512]       16 MB  (dead after proj_kv)
  //  52  xh    f16 [4096 x 512]         4 MB  (dead after Q proj)
  //  36  Opart f16 [128 x 1024 x 128]  32 MB  (aliases ench+xh+12MB fresh)
  //  68  CTXh  f16 [4096 x 512]         4 MB
  //  72  ml    f32 [128 x 1024 x 2]     1 MB
  //  73  Wh    f16 [4 x 512 x 512]      2 MB  (Who needed until final proj)
  //  total 75 MB
  char* ws = (char*)d_ws;
  _Float16* Qh    = (_Float16*)(ws);
  _Float16* Kh    = (_Float16*)(ws + (4u  << 20));
  _Float16* Vtg   = (_Float16*)(ws + (20u << 20));
  _Float16* ench  = (_Float16*)(ws + (36u << 20));
  _Float16* xh    = (_Float16*)(ws + (52u << 20));
  _Float16* Opart = (_Float16*)(ws + (36u << 20));
  _Float16* CTXh  = (_Float16*)(ws + (68u << 20));
  float*    mlp   = (float*)   (ws + (72u << 20));
  _Float16* Wh    = (_Float16*)(ws + (73u << 20));

  _Float16* Whq = Wh;
  _Float16* Whk = Wh + 262144;
  _Float16* Whv = Wh + 524288;
  _Float16* Who = Wh + 786432;

  const float qscale = 0.08838834764831845f;  // 1/sqrt(128)
  dim3 blk(256);

  prep_cast<<<dim3(11264), blk, 0, stream>>>(x, enc, Wq, Wk, Wv, Wo, xh, ench, Wh);

  proj_mfma<1><<<dim3(32, 4), blk, 0, stream>>>(xh, Whq, bq, Qh, qscale);
  proj_kv<<<dim3(128, 4), blk, 0, stream>>>(ench, Whk, Whv, bk, bv, Kh, Vtg);

  flash_mfma2<<<dim3(128, 8), blk, 0, stream>>>(Qh, Kh, Vtg, Opart, mlp);

  combine_splits<<<dim3(8192), blk, 0, stream>>>(Opart, mlp, CTXh);

  proj_mfma<0><<<dim3(32, 4), blk, 0, stream>>>(CTXh, Who, bo, out, 1.f);
}

// Round 7
// 212.724 us; speedup vs baseline: 1.4851x; 1.4851x over previous
//
#include <hip/hip_runtime.h>
#include <math.h>

// Problem constants
#define B_    4
#define LQ_   1024
#define LKV_  4096
#define DM    512    // model dim
#define NH    4
#define HD_   128    // head dim

typedef _Float16 half8   __attribute__((ext_vector_type(8)));
typedef _Float16 half4_t __attribute__((ext_vector_type(4)));
typedef float    floatx4 __attribute__((ext_vector_type(4)));

#define MFMA16(a, b, c) __builtin_amdgcn_mfma_f32_16x16x32_f16((a), (b), (c), 0, 0, 0)

// ---------------------------------------------------------------------------
// prep: cast x, enc, and the 4 weight matrices to f16 in one pass.
// float4 index space: x 524288 | enc 2097152 | W 4x65536  => 2,883,584 total
// ---------------------------------------------------------------------------
__global__ __launch_bounds__(256) void prep_cast(
    const float* __restrict__ x, const float* __restrict__ enc,
    const float* __restrict__ Wq, const float* __restrict__ Wk,
    const float* __restrict__ Wv, const float* __restrict__ Wo,
    _Float16* __restrict__ xh, _Float16* __restrict__ ench,
    _Float16* __restrict__ Wh)
{
  int i = blockIdx.x * 256 + threadIdx.x;
  const float* src; _Float16* dst; size_t off;
  if (i < 524288) { src = x; dst = xh; off = i; }
  else if (i < 2621440) { src = enc; dst = ench; off = i - 524288; }
  else {
    int j = i - 2621440;            // 0..262143
    int wsel = j >> 16;             // 65536 float4 per W
    src = (wsel == 0) ? Wq : (wsel == 1) ? Wk : (wsel == 2) ? Wv : Wo;
    dst = Wh + ((size_t)wsel << 18);
    off = j & 65535;
  }
  float4 v = *(const float4*)(src + off * 4);
  half4_t h;
  h[0] = (_Float16)v.x; h[1] = (_Float16)v.y;
  h[2] = (_Float16)v.z; h[3] = (_Float16)v.w;
  *(half4_t*)(dst + off * 4) = h;
}

// ---------------------------------------------------------------------------
// f16 MFMA GEMM: Y[M,512] = (X @ W^T + bias) * scale. All-f16 inputs.
// MODE 0: f32 out. MODE 1: f16 out.
// Block 256 = 4 waves (2x2 of 64x64), tile 128x128, BK=64.
// A-frag: A[m=lane&15][k=quad*8+j]; B-frag: B[k=quad*8+j][n=lane&15]
// C/D:    row=quad*4+reg, col=lane&15
// ---------------------------------------------------------------------------
template<int MODE>
__global__ __launch_bounds__(256) void proj_mfma(
    const _Float16* __restrict__ X,
    const _Float16* __restrict__ W,
    const float* __restrict__ bias,
    void* __restrict__ Yv, float scale)
{
  __shared__ _Float16 Xs[128][72];
  __shared__ _Float16 Ws[128][72];

  const int tid  = threadIdx.x;
  const int lane = tid & 63;
  const int w    = tid >> 6;
  const int n16  = lane & 15;
  const int quad = lane >> 4;
  const int wm   = (w & 1) * 64;
  const int wn   = (w >> 1) * 64;
  const int row0 = blockIdx.x * 128;
  const int col0 = blockIdx.y * 128;

  floatx4 acc[4][4];
#pragma unroll
  for (int a = 0; a < 4; ++a)
#pragma unroll
    for (int b = 0; b < 4; ++b) acc[a][b] = (floatx4){0.f, 0.f, 0.f, 0.f};

  for (int k0 = 0; k0 < 512; k0 += 64) {
#pragma unroll
    for (int i = 0; i < 4; ++i) {
      int c = i * 256 + tid;
      int r = c >> 3, off = (c & 7) * 8;
      *(half8*)&Xs[r][off] = *(const half8*)(X + (size_t)(row0 + r) * 512 + k0 + off);
      *(half8*)&Ws[r][off] = *(const half8*)(W + (size_t)(col0 + r) * 512 + k0 + off);
    }
    __syncthreads();
#pragma unroll
    for (int kc = 0; kc < 2; ++kc) {
      half8 af[4], bf[4];
#pragma unroll
      for (int mb = 0; mb < 4; ++mb)
        af[mb] = *(const half8*)&Xs[wm + mb * 16 + n16][kc * 32 + quad * 8];
#pragma unroll
      for (int nb = 0; nb < 4; ++nb)
        bf[nb] = *(const half8*)&Ws[wn + nb * 16 + n16][kc * 32 + quad * 8];
#pragma unroll
      for (int mb = 0; mb < 4; ++mb)
#pragma unroll
        for (int nb = 0; nb < 4; ++nb)
          acc[mb][nb] = MFMA16(af[mb], bf[nb], acc[mb][nb]);
    }
    __syncthreads();
  }

#pragma unroll
  for (int mb = 0; mb < 4; ++mb) {
#pragma unroll
    for (int nb = 0; nb < 4; ++nb) {
#pragma unroll
      for (int r = 0; r < 4; ++r) {
        int row = row0 + wm + mb * 16 + quad * 4 + r;
        int col = col0 + wn + nb * 16 + n16;
        float v = (acc[mb][nb][r] + bias[col]) * scale;
        if (MODE == 0) ((float*)Yv)[(size_t)row * 512 + col] = v;
        else ((_Float16*)Yv)[(size_t)row * 512 + col] = (_Float16)v;
      }
    }
  }
}

// ---------------------------------------------------------------------------
// Fused K+V projection: stages the enc tile once, computes K (row-major f16)
// and V (transposed per-head to Vt[(b*4+coly)*128+d][LKV]).
// ---------------------------------------------------------------------------
__global__ __launch_bounds__(256, 2) void proj_kv(
    const _Float16* __restrict__ Xe,     // ench [B*LKV, 512]
    const _Float16* __restrict__ Wk,
    const _Float16* __restrict__ Wv,
    const float* __restrict__ bk,
    const float* __restrict__ bv,
    _Float16* __restrict__ Kh,
    _Float16* __restrict__ Vt)
{
  __shared__ _Float16 SM[3 * 128 * 72];          // 55,296 B
  _Float16 (*Xs)[72]  = (_Float16(*)[72])SM;
  _Float16 (*Wks)[72] = (_Float16(*)[72])(SM + 128 * 72);
  _Float16 (*Wvs)[72] = (_Float16(*)[72])(SM + 2 * 128 * 72);

  const int tid  = threadIdx.x;
  const int lane = tid & 63;
  const int w    = tid >> 6;
  const int n16  = lane & 15;
  const int quad = lane >> 4;
  const int wm   = (w & 1) * 64;
  const int wn   = (w >> 1) * 64;
  const int row0 = blockIdx.x * 128;             // enc row (kv)
  const int col0 = blockIdx.y * 128;             // output col (d)

  floatx4 accK[4][4], accV[4][4];
#pragma unroll
  for (int a = 0; a < 4; ++a)
#pragma unroll
    for (int b = 0; b < 4; ++b) {
      accK[a][b] = (floatx4){0.f, 0.f, 0.f, 0.f};
      accV[a][b] = (floatx4){0.f, 0.f, 0.f, 0.f};
    }

  for (int k0 = 0; k0 < 512; k0 += 64) {
#pragma unroll
    for (int i = 0; i < 4; ++i) {
      int c = i * 256 + tid;
      int r = c >> 3, off = (c & 7) * 8;
      *(half8*)&Xs[r][off]  = *(const half8*)(Xe + (size_t)(row0 + r) * 512 + k0 + off);
      *(half8*)&Wks[r][off] = *(const half8*)(Wk + (size_t)(col0 + r) * 512 + k0 + off);
      *(half8*)&Wvs[r][off] = *(const half8*)(Wv + (size_t)(col0 + r) * 512 + k0 + off);
    }
    __syncthreads();
#pragma unroll
    for (int kc = 0; kc < 2; ++kc) {
      half8 af[4], bkf[4], bvf[4];
#pragma unroll
      for (int mb = 0; mb < 4; ++mb)
        af[mb] = *(const half8*)&Xs[wm + mb * 16 + n16][kc * 32 + quad * 8];
#pragma unroll
      for (int nb = 0; nb < 4; ++nb) {
        bkf[nb] = *(const half8*)&Wks[wn + nb * 16 + n16][kc * 32 + quad * 8];
        bvf[nb] = *(const half8*)&Wvs[wn + nb * 16 + n16][kc * 32 + quad * 8];
      }
#pragma unroll
      for (int mb = 0; mb < 4; ++mb)
#pragma unroll
        for (int nb = 0; nb < 4; ++nb) {
          accK[mb][nb] = MFMA16(af[mb], bkf[nb], accK[mb][nb]);
          accV[mb][nb] = MFMA16(af[mb], bvf[nb], accV[mb][nb]);
        }
    }
    __syncthreads();
  }

  // K epilogue: row-major f16
#pragma unroll
  for (int mb = 0; mb < 4; ++mb) {
#pragma unroll
    for (int nb = 0; nb < 4; ++nb) {
#pragma unroll
      for (int r = 0; r < 4; ++r) {
        int row = row0 + wm + mb * 16 + quad * 4 + r;
        int col = col0 + wn + nb * 16 + n16;
        Kh[(size_t)row * 512 + col] = (_Float16)(accK[mb][nb][r] + bk[col]);
      }
    }
  }

  // V epilogue: transpose through LDS. acc rows = kv, cols = d.
  _Float16 (*Ts)[144] = (_Float16(*)[144])SM;    // 128 x 144 fits in SM
#pragma unroll
  for (int mb = 0; mb < 4; ++mb) {
#pragma unroll
    for (int nb = 0; nb < 4; ++nb) {
      int dl = wn + nb * 16 + n16;
      float bi = bv[col0 + dl];
      half4_t hv;
#pragma unroll
      for (int r = 0; r < 4; ++r) hv[r] = (_Float16)(accV[mb][nb][r] + bi);
      *(half4_t*)&Ts[dl][wm + mb * 16 + quad * 4] = hv;
    }
  }
  __syncthreads();
  int b   = row0 >> 12;
  int kv0 = row0 & 4095;
#pragma unroll
  for (int i = 0; i < 8; ++i) {
    int f = i * 256 + tid;
    int dl = f >> 4, kv8 = (f & 15) * 8;
    half8 ov = *(const half8*)&Ts[dl][kv8];
    *(half8*)(Vt + (size_t)((b * 4 + blockIdx.y) * 128 + dl) * LKV_ + kv0 + kv8) = ov;
  }
}

// ---------------------------------------------------------------------------
// Flash attention, S^T form, split-KV x8. Block = 4 waves x 32 q = 128 q.
// P buffer ALIASES the K-tile LDS (P is per-wave-private; extra barrier
// after S-MFMAs protects cross-wave K reads). LDS 36 KB.
// __launch_bounds__(256,2): round-6's (256,4) clamped VGPRs to 64 and the
// ~130-reg live set spilled to scratch (FETCH 377 MB / WRITE 263 MB of
// spill traffic, flash 165 us). At ~120 VGPR the HW reaches 4 blocks/CU
// on its own (LDS 36 KB, 120<=128 VGPR).
// ---------------------------------------------------------------------------
__global__ __launch_bounds__(256, 2) void flash_mfma2(
    const _Float16* __restrict__ Qh,   // [B*LQ, 512], pre-scaled
    const _Float16* __restrict__ Kh,   // [B*LKV, 512]
    const _Float16* __restrict__ Vtg,  // [B*NH*HD, LKV], d-major
    _Float16* __restrict__ Opart,      // [128][1024][128] f16 unnormalized
    float* __restrict__ ml)            // [128][1024][2]
{
  __shared__ _Float16 U[4 * 32 * 72];  // 18,432 B: K tiles (64x136=8704) | P (4x32x72)
  __shared__ _Float16 Vs[128][72];     // 18,432 B: V tile, d-major
  _Float16 (*Ks)[136] = (_Float16(*)[136])U;
  _Float16* Ps = U;                    // [4][32][72] alias

  const int tid  = threadIdx.x;
  const int lane = tid & 63;
  const int w    = tid >> 6;
  const int n16  = lane & 15;
  const int quad = lane >> 4;

  const int xb    = blockIdx.x;        // bh*8 + split  (128)
  const int qt    = blockIdx.y;        // 0..7, 128 q each
  const int split = xb & 7;
  const int bh    = xb >> 3;
  const int h = bh & 3, b = bh >> 2;

  const _Float16* Qg = Qh + (size_t)(b * LQ_ + qt * 128) * DM + h * HD_;
  const _Float16* Kg = Kh + (size_t)(b * LKV_) * DM + h * HD_;
  const _Float16* Vg = Vtg + (size_t)(bh * HD_) * LKV_;

  // load Q frags for this wave (q = w*32 + qb*16 + n16) via 2 chunks through Ks
  half8 qf[2][4];
  const int chunk = w >> 1;
  const int qrb   = (w & 1) * 32;
#pragma unroll
  for (int c = 0; c < 2; ++c) {
#pragma unroll
    for (int i = 0; i < 4; ++i) {
      int f = i * 256 + tid;
      int r = f >> 4, c8 = (f & 15) * 8;
      *(half8*)&Ks[r][c8] = *(const half8*)(Qg + (size_t)(c * 64 + r) * DM + c8);
    }
    __syncthreads();
    if (chunk == c) {
#pragma unroll
      for (int qb = 0; qb < 2; ++qb)
#pragma unroll
        for (int kc = 0; kc < 4; ++kc)
          qf[qb][kc] = *(const half8*)&Ks[qrb + qb * 16 + n16][kc * 32 + quad * 8];
    }
    __syncthreads();
  }

  floatx4 o[2][8];
#pragma unroll
  for (int mb = 0; mb < 2; ++mb)
#pragma unroll
    for (int vb = 0; vb < 8; ++vb) o[mb][vb] = (floatx4){0.f, 0.f, 0.f, 0.f};
  float m_i[2] = {-INFINITY, -INFINITY};
  float l_i[2] = {0.f, 0.f};

  for (int kt = split * 8; kt < split * 8 + 8; ++kt) {
    // stage K (64 kv x 128 d) and V (128 d x 64 kv)
#pragma unroll
    for (int i = 0; i < 4; ++i) {
      int f = i * 256 + tid;
      int r = f >> 4, c8 = (f & 15) * 8;
      *(half8*)&Ks[r][c8] = *(const half8*)(Kg + (size_t)(kt * 64 + r) * DM + c8);
    }
#pragma unroll
    for (int i = 0; i < 4; ++i) {
      int f = i * 256 + tid;
      int d = f >> 3, kv8 = (f & 7) * 8;
      *(half8*)&Vs[d][kv8] = *(const half8*)(Vg + (size_t)d * LKV_ + kt * 64 + kv8);
    }
    __syncthreads();

    // S^T per wave: rows kv=cb*16+quad*4+r, col q=qb*16+n16
    floatx4 s[2][4];
#pragma unroll
    for (int qb = 0; qb < 2; ++qb)
#pragma unroll
      for (int cb = 0; cb < 4; ++cb) s[qb][cb] = (floatx4){0.f, 0.f, 0.f, 0.f};
#pragma unroll
    for (int cb = 0; cb < 4; ++cb) {
#pragma unroll
      for (int kc = 0; kc < 4; ++kc) {
        half8 kf = *(const half8*)&Ks[cb * 16 + n16][kc * 32 + quad * 8];
        s[0][cb] = MFMA16(kf, qf[0][kc], s[0][cb]);
        s[1][cb] = MFMA16(kf, qf[1][kc], s[1][cb]);
      }
    }
    __syncthreads();   // all waves done reading Ks before P (aliased) overwrites

    // online softmax per q column; reduce across quads (xor 16, 32)
    float alpha[2];
#pragma unroll
    for (int qb = 0; qb < 2; ++qb) {
      float mx = -INFINITY;
#pragma unroll
      for (int cb = 0; cb < 4; ++cb)
#pragma unroll
        for (int r = 0; r < 4; ++r) mx = fmaxf(mx, s[qb][cb][r]);
      mx = fmaxf(mx, __shfl_xor(mx, 16));
      mx = fmaxf(mx, __shfl_xor(mx, 32));
      float mn = fmaxf(m_i[qb], mx);
      alpha[qb] = __expf(m_i[qb] - mn);
      m_i[qb] = mn;
      float rs = 0.f;
#pragma unroll
      for (int cb = 0; cb < 4; ++cb) {
        half4_t ph;
#pragma unroll
        for (int r = 0; r < 4; ++r) {
          float p = __expf(s[qb][cb][r] - mn);
          rs += p;
          ph[r] = (_Float16)p;
        }
        *(half4_t*)&Ps[(w * 32 + qb * 16 + n16) * 72 + cb * 16 + quad * 4] = ph;
      }
      rs += __shfl_xor(rs, 16);
      rs += __shfl_xor(rs, 32);
      l_i[qb] = l_i[qb] * alpha[qb] + rs;
    }

    // rescale O: row q = mb*16 + quad*4 + r -> alpha from lane n16=quad*4+r
#pragma unroll
    for (int mb = 0; mb < 2; ++mb) {
#pragma unroll
      for (int r = 0; r < 4; ++r) {
        float a = __shfl(alpha[mb], (lane & 48) | (quad * 4 + r));
#pragma unroll
        for (int vb = 0; vb < 8; ++vb) o[mb][vb][r] *= a;
      }
    }

    // O += P V  (P from per-wave LDS slice; intra-wave ordering)
    half8 pf[2][2];
#pragma unroll
    for (int mb = 0; mb < 2; ++mb)
#pragma unroll
      for (int kc = 0; kc < 2; ++kc)
        pf[mb][kc] = *(const half8*)&Ps[(w * 32 + mb * 16 + n16) * 72 + kc * 32 + quad * 8];
#pragma unroll
    for (int vb = 0; vb < 8; ++vb) {
#pragma unroll
      for (int kc = 0; kc < 2; ++kc) {
        half8 vf = *(const half8*)&Vs[vb * 16 + n16][kc * 32 + quad * 8];
        o[0][vb] = MFMA16(pf[0][kc], vf, o[0][vb]);
        o[1][vb] = MFMA16(pf[1][kc], vf, o[1][vb]);
      }
    }
    __syncthreads();   // P (and Vs) free before next stage
  }

  // write unnormalized partial O (f16) and (m,l)
  _Float16* Og = Opart + ((size_t)xb * 1024 + qt * 128 + w * 32) * HD_;
#pragma unroll
  for (int mb = 0; mb < 2; ++mb) {
#pragma unroll
    for (int r = 0; r < 4; ++r) {
#pragma unroll
      for (int vb = 0; vb < 8; ++vb)
        Og[(size_t)(mb * 16 + quad * 4 + r) * HD_ + vb * 16 + n16] =
            (_Float16)o[mb][vb][r];
    }
  }
  if (quad == 0) {
#pragma unroll
    for (int qb = 0; qb < 2; ++qb) {
      size_t qi = (size_t)xb * 1024 + qt * 128 + w * 32 + qb * 16 + n16;
      ml[qi * 2] = m_i[qb];
      ml[qi * 2 + 1] = l_i[qb];
    }
  }
}

// ---------------------------------------------------------------------------
// Combine 8 KV-split partials -> CTXh f16 [B*LQ, 512]
// ---------------------------------------------------------------------------
__global__ __launch_bounds__(256) void combine_splits(
    const _Float16* __restrict__ Opart,
    const float* __restrict__ ml,
    _Float16* __restrict__ CTXh)
{
  int g  = blockIdx.x * 2 + (threadIdx.x >> 7);   // row 0..16383 (bh*1024+q)
  int d  = threadIdx.x & 127;
  int bh = g >> 10, q = g & 1023;
  int b = bh >> 2, h = bh & 3;

  float m[8], l[8], M = -INFINITY;
#pragma unroll
  for (int p = 0; p < 8; ++p) {
    size_t idx = ((size_t)(bh * 8 + p) * 1024 + q) * 2;
    m[p] = ml[idx]; l[p] = ml[idx + 1];
    M = fmaxf(M, m[p]);
  }
  float L = 0.f, o = 0.f;
#pragma unroll
  for (int p = 0; p < 8; ++p) {
    float wgt = __expf(m[p] - M);
    L += wgt * l[p];
    o += wgt * (float)Opart[((size_t)(bh * 8 + p) * 1024 + q) * HD_ + d];
  }
  CTXh[(size_t)(b * LQ_ + q) * DM + h * HD_ + d] = (_Float16)(o / L);
}

// ---------------------------------------------------------------------------
extern "C" void kernel_launch(void* const* d_in, const int* in_sizes, int n_in,
                              void* d_out, int out_size, void* d_ws, size_t ws_size,
                              hipStream_t stream) {
  const float* x   = (const float*)d_in[0];
  const float* enc = (const float*)d_in[1];
  const float* Wq  = (const float*)d_in[2];
  const float* Wk  = (const float*)d_in[3];
  const float* Wv  = (const float*)d_in[4];
  const float* bq  = (const float*)d_in[5];
  const float* bk  = (const float*)d_in[6];
  const float* bv  = (const float*)d_in[7];
  const float* Wo  = (const float*)d_in[8];
  const float* bo  = (const float*)d_in[9];
  float* out = (float*)d_out;

  // workspace layout (MB offsets):
  //   0  Qh    f16 [4096 x 512]         4 MB
  //   4  Kh    f16 [16384 x 512]       16 MB
  //  20  Vtg   f16 [2048 x 4096]       16 MB
  //  36  ench  f16 [16384 x 512]       16 MB  (dead after proj_kv)
  //  52  xh    f16 [4096 x 512]         4 MB  (dead after Q proj)
  //  36  Opart f16 [128 x 1024 x 128]  32 MB  (aliases ench+xh+12MB fresh)
  //  68  CTXh  f16 [4096 x 512]         4 MB
  //  72  ml    f32 [128 x 1024 x 2]     1 MB
  //  73  Wh    f16 [4 x 512 x 512]      2 MB  (Who needed until final proj)
  //  total 75 MB
  char* ws = (char*)d_ws;
  _Float16* Qh    = (_Float16*)(ws);
  _Float16* Kh    = (_Float16*)(ws + (4u  << 20));
  _Float16* Vtg   = (_Float16*)(ws + (20u << 20));
  _Float16* ench  = (_Float16*)(ws + (36u << 20));
  _Float16* xh    = (_Float16*)(ws + (52u << 20));
  _Float16* Opart = (_Float16*)(ws + (36u << 20));
  _Float16* CTXh  = (_Float16*)(ws + (68u << 20));
  float*    mlp   = (float*)   (ws + (72u << 20));
  _Float16* Wh    = (_Float16*)(ws + (73u << 20));

  _Float16* Whq = Wh;
  _Float16* Whk = Wh + 262144;
  _Float16* Whv = Wh + 524288;
  _Float16* Who = Wh + 786432;

  const float qscale = 0.08838834764831845f;  // 1/sqrt(128)
  dim3 blk(256);

  prep_cast<<<dim3(11264), blk, 0, stream>>>(x, enc, Wq, Wk, Wv, Wo, xh, ench, Wh);

  proj_mfma<1><<<dim3(32, 4), blk, 0, stream>>>(xh, Whq, bq, Qh, qscale);
  proj_kv<<<dim3(128, 4), blk, 0, stream>>>(ench, Whk, Whv, bk, bv, Kh, Vtg);

  flash_mfma2<<<dim3(128, 8), blk, 0, stream>>>(Qh, Kh, Vtg, Opart, mlp);

  combine_splits<<<dim3(8192), blk, 0, stream>>>(Opart, mlp, CTXh);

  proj_mfma<0><<<dim3(32, 4), blk, 0, stream>>>(CTXh, Who, bo, out, 1.f);
}

// Round 8
// 202.286 us; speedup vs baseline: 1.5618x; 1.0516x over previous
//
#include <hip/hip_runtime.h>
#include <math.h>

// Problem constants
#define B_    4
#define LQ_   1024
#define LKV_  4096
#define DM    512    // model dim
#define NH    4
#define HD_   128    // head dim

typedef _Float16 half8   __attribute__((ext_vector_type(8)));
typedef _Float16 half4_t __attribute__((ext_vector_type(4)));
typedef float    floatx4 __attribute__((ext_vector_type(4)));

#define MFMA16(a, b, c) __builtin_amdgcn_mfma_f32_16x16x32_f16((a), (b), (c), 0, 0, 0)

// ---------------------------------------------------------------------------
// prep: cast the 4 weight matrices to f16 (weights are re-read ~128x by the
// projections, so pre-casting them pays; x/enc casts are fused into staging).
// 4 x 262144 f32 = 262144 float4 -> 1024 blocks.
// ---------------------------------------------------------------------------
__global__ __launch_bounds__(256) void prep_w(
    const float* __restrict__ Wq, const float* __restrict__ Wk,
    const float* __restrict__ Wv, const float* __restrict__ Wo,
    _Float16* __restrict__ Wh)
{
  int i = blockIdx.x * 256 + threadIdx.x;   // 0..262143
  int wsel = i >> 16;                       // 65536 float4 per W
  const float* src = (wsel == 0) ? Wq : (wsel == 1) ? Wk : (wsel == 2) ? Wv : Wo;
  size_t off = i & 65535;
  float4 v = *(const float4*)(src + off * 4);
  half4_t h;
  h[0] = (_Float16)v.x; h[1] = (_Float16)v.y;
  h[2] = (_Float16)v.z; h[3] = (_Float16)v.w;
  *(half4_t*)(Wh + ((size_t)wsel << 18) + off * 4) = h;
}

// ---------------------------------------------------------------------------
// Fused Q+K+V projection. Grid (160, 4):
//   bx <  128 : KV path — dual GEMM vs enc rows [bx*128, +128):
//               K row-major f16, V transposed per-head to Vt.
//   bx >= 128 : Q path  — GEMM vs x rows [(bx-128)*128, +128), f16 out *qscale.
// X staged from f32 with inline cvt; W from pre-cast f16.
// A-frag: A[m=lane&15][k=quad*8+j]; B-frag: B[k=quad*8+j][n=lane&15]
// C/D:    row=quad*4+reg, col=lane&15
// ---------------------------------------------------------------------------
__global__ __launch_bounds__(256, 2) void proj_qkv(
    const float* __restrict__ x,       // [4096, 512] f32
    const float* __restrict__ enc,     // [16384, 512] f32
    const _Float16* __restrict__ Whq,
    const _Float16* __restrict__ Whk,
    const _Float16* __restrict__ Whv,
    const float* __restrict__ bq,
    const float* __restrict__ bk,
    const float* __restrict__ bv,
    _Float16* __restrict__ Qh,
    _Float16* __restrict__ Kh,
    _Float16* __restrict__ Vt,
    float qscale)
{
  __shared__ _Float16 SM[3 * 128 * 72];          // 55,296 B
  _Float16 (*Xs)[72]  = (_Float16(*)[72])SM;
  _Float16 (*Ws1)[72] = (_Float16(*)[72])(SM + 128 * 72);
  _Float16 (*Ws2)[72] = (_Float16(*)[72])(SM + 2 * 128 * 72);

  const int tid  = threadIdx.x;
  const int lane = tid & 63;
  const int w    = tid >> 6;
  const int n16  = lane & 15;
  const int quad = lane >> 4;
  const int wm   = (w & 1) * 64;
  const int wn   = (w >> 1) * 64;
  const int col0 = blockIdx.y * 128;

  if ((int)blockIdx.x >= 128) {
    // ---------------- Q path ----------------
    const int row0 = ((int)blockIdx.x - 128) * 128;
    floatx4 acc[4][4];
#pragma unroll
    for (int a = 0; a < 4; ++a)
#pragma unroll
      for (int b = 0; b < 4; ++b) acc[a][b] = (floatx4){0.f, 0.f, 0.f, 0.f};

    for (int k0 = 0; k0 < 512; k0 += 64) {
#pragma unroll
      for (int i = 0; i < 4; ++i) {
        int c = i * 256 + tid;
        int r = c >> 3, off = (c & 7) * 8;
        const float* xp = x + (size_t)(row0 + r) * 512 + k0 + off;
        float4 a = *(const float4*)xp, b2 = *(const float4*)(xp + 4);
        half8 hx;
        hx[0] = (_Float16)a.x;  hx[1] = (_Float16)a.y;
        hx[2] = (_Float16)a.z;  hx[3] = (_Float16)a.w;
        hx[4] = (_Float16)b2.x; hx[5] = (_Float16)b2.y;
        hx[6] = (_Float16)b2.z; hx[7] = (_Float16)b2.w;
        *(half8*)&Xs[r][off] = hx;
        *(half8*)&Ws1[r][off] = *(const half8*)(Whq + (size_t)(col0 + r) * 512 + k0 + off);
      }
      __syncthreads();
#pragma unroll
      for (int kc = 0; kc < 2; ++kc) {
        half8 af[4], bf[4];
#pragma unroll
        for (int mb = 0; mb < 4; ++mb)
          af[mb] = *(const half8*)&Xs[wm + mb * 16 + n16][kc * 32 + quad * 8];
#pragma unroll
        for (int nb = 0; nb < 4; ++nb)
          bf[nb] = *(const half8*)&Ws1[wn + nb * 16 + n16][kc * 32 + quad * 8];
#pragma unroll
        for (int mb = 0; mb < 4; ++mb)
#pragma unroll
          for (int nb = 0; nb < 4; ++nb)
            acc[mb][nb] = MFMA16(af[mb], bf[nb], acc[mb][nb]);
      }
      __syncthreads();
    }
#pragma unroll
    for (int mb = 0; mb < 4; ++mb)
#pragma unroll
      for (int nb = 0; nb < 4; ++nb)
#pragma unroll
        for (int r = 0; r < 4; ++r) {
          int row = row0 + wm + mb * 16 + quad * 4 + r;
          int col = col0 + wn + nb * 16 + n16;
          Qh[(size_t)row * 512 + col] =
              (_Float16)((acc[mb][nb][r] + bq[col]) * qscale);
        }
    return;
  }

  // ---------------- KV path ----------------
  const int row0 = (int)blockIdx.x * 128;
  floatx4 accK[4][4], accV[4][4];
#pragma unroll
  for (int a = 0; a < 4; ++a)
#pragma unroll
    for (int b = 0; b < 4; ++b) {
      accK[a][b] = (floatx4){0.f, 0.f, 0.f, 0.f};
      accV[a][b] = (floatx4){0.f, 0.f, 0.f, 0.f};
    }

  for (int k0 = 0; k0 < 512; k0 += 64) {
#pragma unroll
    for (int i = 0; i < 4; ++i) {
      int c = i * 256 + tid;
      int r = c >> 3, off = (c & 7) * 8;
      const float* xp = enc + (size_t)(row0 + r) * 512 + k0 + off;
      float4 a = *(const float4*)xp, b2 = *(const float4*)(xp + 4);
      half8 hx;
      hx[0] = (_Float16)a.x;  hx[1] = (_Float16)a.y;
      hx[2] = (_Float16)a.z;  hx[3] = (_Float16)a.w;
      hx[4] = (_Float16)b2.x; hx[5] = (_Float16)b2.y;
      hx[6] = (_Float16)b2.z; hx[7] = (_Float16)b2.w;
      *(half8*)&Xs[r][off] = hx;
      *(half8*)&Ws1[r][off] = *(const half8*)(Whk + (size_t)(col0 + r) * 512 + k0 + off);
      *(half8*)&Ws2[r][off] = *(const half8*)(Whv + (size_t)(col0 + r) * 512 + k0 + off);
    }
    __syncthreads();
#pragma unroll
    for (int kc = 0; kc < 2; ++kc) {
      half8 af[4], bkf[4], bvf[4];
#pragma unroll
      for (int mb = 0; mb < 4; ++mb)
        af[mb] = *(const half8*)&Xs[wm + mb * 16 + n16][kc * 32 + quad * 8];
#pragma unroll
      for (int nb = 0; nb < 4; ++nb) {
        bkf[nb] = *(const half8*)&Ws1[wn + nb * 16 + n16][kc * 32 + quad * 8];
        bvf[nb] = *(const half8*)&Ws2[wn + nb * 16 + n16][kc * 32 + quad * 8];
      }
#pragma unroll
      for (int mb = 0; mb < 4; ++mb)
#pragma unroll
        for (int nb = 0; nb < 4; ++nb) {
          accK[mb][nb] = MFMA16(af[mb], bkf[nb], accK[mb][nb]);
          accV[mb][nb] = MFMA16(af[mb], bvf[nb], accV[mb][nb]);
        }
    }
    __syncthreads();
  }

  // K epilogue: row-major f16
#pragma unroll
  for (int mb = 0; mb < 4; ++mb)
#pragma unroll
    for (int nb = 0; nb < 4; ++nb)
#pragma unroll
      for (int r = 0; r < 4; ++r) {
        int row = row0 + wm + mb * 16 + quad * 4 + r;
        int col = col0 + wn + nb * 16 + n16;
        Kh[(size_t)row * 512 + col] = (_Float16)(accK[mb][nb][r] + bk[col]);
      }

  // V epilogue: transpose through LDS (acc rows = kv, cols = d).
  _Float16 (*Ts)[144] = (_Float16(*)[144])SM;    // 36,864 B <= 55,296 B
#pragma unroll
  for (int mb = 0; mb < 4; ++mb)
#pragma unroll
    for (int nb = 0; nb < 4; ++nb) {
      int dl = wn + nb * 16 + n16;
      float bi = bv[col0 + dl];
      half4_t hv;
#pragma unroll
      for (int r = 0; r < 4; ++r) hv[r] = (_Float16)(accV[mb][nb][r] + bi);
      *(half4_t*)&Ts[dl][wm + mb * 16 + quad * 4] = hv;
    }
  __syncthreads();
  int b   = row0 >> 12;
  int kv0 = row0 & 4095;
#pragma unroll
  for (int i = 0; i < 8; ++i) {            // 128 d x 128 kv = 2048 half8 stores
    int f = i * 256 + tid;
    int dl = f >> 4, kv8 = (f & 15) * 8;
    half8 ov = *(const half8*)&Ts[dl][kv8];
    *(half8*)(Vt + (size_t)((b * 4 + blockIdx.y) * 128 + dl) * LKV_ + kv0 + kv8) = ov;
  }
}

// ---------------------------------------------------------------------------
// Flash attention, S^T form, split-KV x4. Block = 4 waves x 32 q = 128 q.
// P buffer ALIASES the K-tile LDS; extra barrier after S-MFMAs protects
// cross-wave K reads. LDS 36 KB. __launch_bounds__(256,2): (256,4) round-6
// clamp caused catastrophic VGPR spill.
// Rescale-skip: when no q-row saw a new max (alpha==1 for all lanes), the
// O-rescale (64 v_mul + 8 shfl) is skipped via wave vote.
// ---------------------------------------------------------------------------
__global__ __launch_bounds__(256, 2) void flash_mfma2(
    const _Float16* __restrict__ Qh,   // [B*LQ, 512], pre-scaled
    const _Float16* __restrict__ Kh,   // [B*LKV, 512]
    const _Float16* __restrict__ Vtg,  // [B*NH*HD, LKV], d-major
    _Float16* __restrict__ Opart,      // [64][1024][128] f16 unnormalized
    float* __restrict__ ml)            // [64][1024][2]
{
  __shared__ _Float16 U[4 * 32 * 72];  // 18,432 B: K tile (64x136) | P alias
  __shared__ _Float16 Vs[128][72];     // 18,432 B: V tile, d-major
  _Float16 (*Ks)[136] = (_Float16(*)[136])U;
  _Float16* Ps = U;                    // [4][32][72] alias

  const int tid  = threadIdx.x;
  const int lane = tid & 63;
  const int w    = tid >> 6;
  const int n16  = lane & 15;
  const int quad = lane >> 4;

  const int xb    = blockIdx.x;        // bh*4 + split  (64)
  const int qt    = blockIdx.y;        // 0..7, 128 q each
  const int split = xb & 3;
  const int bh    = xb >> 2;
  const int h = bh & 3, b = bh >> 2;

  const _Float16* Qg = Qh + (size_t)(b * LQ_ + qt * 128) * DM + h * HD_;
  const _Float16* Kg = Kh + (size_t)(b * LKV_) * DM + h * HD_;
  const _Float16* Vg = Vtg + (size_t)(bh * HD_) * LKV_;

  // load Q frags for this wave (q = w*32 + qb*16 + n16) via 2 chunks through Ks
  half8 qf[2][4];
  const int chunk = w >> 1;
  const int qrb   = (w & 1) * 32;
#pragma unroll
  for (int c = 0; c < 2; ++c) {
#pragma unroll
    for (int i = 0; i < 4; ++i) {
      int f = i * 256 + tid;
      int r = f >> 4, c8 = (f & 15) * 8;
      *(half8*)&Ks[r][c8] = *(const half8*)(Qg + (size_t)(c * 64 + r) * DM + c8);
    }
    __syncthreads();
    if (chunk == c) {
#pragma unroll
      for (int qb = 0; qb < 2; ++qb)
#pragma unroll
        for (int kc = 0; kc < 4; ++kc)
          qf[qb][kc] = *(const half8*)&Ks[qrb + qb * 16 + n16][kc * 32 + quad * 8];
    }
    __syncthreads();
  }

  floatx4 o[2][8];
#pragma unroll
  for (int mb = 0; mb < 2; ++mb)
#pragma unroll
    for (int vb = 0; vb < 8; ++vb) o[mb][vb] = (floatx4){0.f, 0.f, 0.f, 0.f};
  float m_i[2] = {-INFINITY, -INFINITY};
  float l_i[2] = {0.f, 0.f};

  for (int kt = split * 16; kt < split * 16 + 16; ++kt) {
    // stage K (64 kv x 128 d) and V (128 d x 64 kv)
#pragma unroll
    for (int i = 0; i < 4; ++i) {
      int f = i * 256 + tid;
      int r = f >> 4, c8 = (f & 15) * 8;
      *(half8*)&Ks[r][c8] = *(const half8*)(Kg + (size_t)(kt * 64 + r) * DM + c8);
    }
#pragma unroll
    for (int i = 0; i < 4; ++i) {
      int f = i * 256 + tid;
      int d = f >> 3, kv8 = (f & 7) * 8;
      *(half8*)&Vs[d][kv8] = *(const half8*)(Vg + (size_t)d * LKV_ + kt * 64 + kv8);
    }
    __syncthreads();

    // S^T per wave: rows kv=cb*16+quad*4+r, col q=qb*16+n16
    floatx4 s[2][4];
#pragma unroll
    for (int qb = 0; qb < 2; ++qb)
#pragma unroll
      for (int cb = 0; cb < 4; ++cb) s[qb][cb] = (floatx4){0.f, 0.f, 0.f, 0.f};
#pragma unroll
    for (int cb = 0; cb < 4; ++cb) {
#pragma unroll
      for (int kc = 0; kc < 4; ++kc) {
        half8 kf = *(const half8*)&Ks[cb * 16 + n16][kc * 32 + quad * 8];
        s[0][cb] = MFMA16(kf, qf[0][kc], s[0][cb]);
        s[1][cb] = MFMA16(kf, qf[1][kc], s[1][cb]);
      }
    }
    __syncthreads();   // all waves done reading Ks before P (aliased) overwrites

    // online softmax per q column; reduce across quads (xor 16, 32)
    float alpha[2];
#pragma unroll
    for (int qb = 0; qb < 2; ++qb) {
      float mx = -INFINITY;
#pragma unroll
      for (int cb = 0; cb < 4; ++cb)
#pragma unroll
        for (int r = 0; r < 4; ++r) mx = fmaxf(mx, s[qb][cb][r]);
      mx = fmaxf(mx, __shfl_xor(mx, 16));
      mx = fmaxf(mx, __shfl_xor(mx, 32));
      float mn = fmaxf(m_i[qb], mx);
      alpha[qb] = __expf(m_i[qb] - mn);
      m_i[qb] = mn;
      float rs = 0.f;
#pragma unroll
      for (int cb = 0; cb < 4; ++cb) {
        half4_t ph;
#pragma unroll
        for (int r = 0; r < 4; ++r) {
          float p = __expf(s[qb][cb][r] - mn);
          rs += p;
          ph[r] = (_Float16)p;
        }
        *(half4_t*)&Ps[(w * 32 + qb * 16 + n16) * 72 + cb * 16 + quad * 4] = ph;
      }
      rs += __shfl_xor(rs, 16);
      rs += __shfl_xor(rs, 32);
      l_i[qb] = l_i[qb] * alpha[qb] + rs;
    }

    // rescale O only if some q-row saw a new max (wave-uniform vote)
    if (__ballot((alpha[0] != 1.f) || (alpha[1] != 1.f))) {
#pragma unroll
      for (int mb = 0; mb < 2; ++mb) {
#pragma unroll
        for (int r = 0; r < 4; ++r) {
          float a = __shfl(alpha[mb], (lane & 48) | (quad * 4 + r));
#pragma unroll
          for (int vb = 0; vb < 8; ++vb) o[mb][vb][r] *= a;
        }
      }
    }

    // O += P V  (P from per-wave LDS slice; intra-wave ordering)
    half8 pf[2][2];
#pragma unroll
    for (int mb = 0; mb < 2; ++mb)
#pragma unroll
      for (int kc = 0; kc < 2; ++kc)
        pf[mb][kc] = *(const half8*)&Ps[(w * 32 + mb * 16 + n16) * 72 + kc * 32 + quad * 8];
#pragma unroll
    for (int vb = 0; vb < 8; ++vb) {
#pragma unroll
      for (int kc = 0; kc < 2; ++kc) {
        half8 vf = *(const half8*)&Vs[vb * 16 + n16][kc * 32 + quad * 8];
        o[0][vb] = MFMA16(pf[0][kc], vf, o[0][vb]);
        o[1][vb] = MFMA16(pf[1][kc], vf, o[1][vb]);
      }
    }
    __syncthreads();   // P (and Vs) free before next stage
  }

  // write unnormalized partial O (f16) and (m,l)
  _Float16* Og = Opart + ((size_t)xb * 1024 + qt * 128 + w * 32) * HD_;
#pragma unroll
  for (int mb = 0; mb < 2; ++mb)
#pragma unroll
    for (int r = 0; r < 4; ++r)
#pragma unroll
      for (int vb = 0; vb < 8; ++vb)
        Og[(size_t)(mb * 16 + quad * 4 + r) * HD_ + vb * 16 + n16] =
            (_Float16)o[mb][vb][r];
  if (quad == 0) {
#pragma unroll
    for (int qb = 0; qb < 2; ++qb) {
      size_t qi = (size_t)xb * 1024 + qt * 128 + w * 32 + qb * 16 + n16;
      ml[qi * 2] = m_i[qb];
      ml[qi * 2 + 1] = l_i[qb];
    }
  }
}

// ---------------------------------------------------------------------------
// Combine 4 KV-split partials -> CTXh f16 [B*LQ, 512]
// ---------------------------------------------------------------------------
__global__ __launch_bounds__(256) void combine_splits(
    const _Float16* __restrict__ Opart,
    const float* __restrict__ ml,
    _Float16* __restrict__ CTXh)
{
  int g  = blockIdx.x * 2 + (threadIdx.x >> 7);   // row 0..16383 (bh*1024+q)
  int d  = threadIdx.x & 127;
  int bh = g >> 10, q = g & 1023;
  int b = bh >> 2, h = bh & 3;

  float m[4], l[4], M = -INFINITY;
#pragma unroll
  for (int p = 0; p < 4; ++p) {
    size_t idx = ((size_t)(bh * 4 + p) * 1024 + q) * 2;
    m[p] = ml[idx]; l[p] = ml[idx + 1];
    M = fmaxf(M, m[p]);
  }
  float L = 0.f, o = 0.f;
#pragma unroll
  for (int p = 0; p < 4; ++p) {
    float wgt = __expf(m[p] - M);
    L += wgt * l[p];
    o += wgt * (float)Opart[((size_t)(bh * 4 + p) * 1024 + q) * HD_ + d];
  }
  CTXh[(size_t)(b * LQ_ + q) * DM + h * HD_ + d] = (_Float16)(o / L);
}

// ---------------------------------------------------------------------------
// Output projection: out[4096,512] f32 = CTXh f16 @ Who^T + bo
// ---------------------------------------------------------------------------
__global__ __launch_bounds__(256) void proj_out(
    const _Float16* __restrict__ X,
    const _Float16* __restrict__ W,
    const float* __restrict__ bias,
    float* __restrict__ Y)
{
  __shared__ _Float16 Xs[128][72];
  __shared__ _Float16 Ws[128][72];

  const int tid  = threadIdx.x;
  const int lane = tid & 63;
  const int w    = tid >> 6;
  const int n16  = lane & 15;
  const int quad = lane >> 4;
  const int wm   = (w & 1) * 64;
  const int wn   = (w >> 1) * 64;
  const int row0 = blockIdx.x * 128;
  const int col0 = blockIdx.y * 128;

  floatx4 acc[4][4];
#pragma unroll
  for (int a = 0; a < 4; ++a)
#pragma unroll
    for (int b = 0; b < 4; ++b) acc[a][b] = (floatx4){0.f, 0.f, 0.f, 0.f};

  for (int k0 = 0; k0 < 512; k0 += 64) {
#pragma unroll
    for (int i = 0; i < 4; ++i) {
      int c = i * 256 + tid;
      int r = c >> 3, off = (c & 7) * 8;
      *(half8*)&Xs[r][off] = *(const half8*)(X + (size_t)(row0 + r) * 512 + k0 + off);
      *(half8*)&Ws[r][off] = *(const half8*)(W + (size_t)(col0 + r) * 512 + k0 + off);
    }
    __syncthreads();
#pragma unroll
    for (int kc = 0; kc < 2; ++kc) {
      half8 af[4], bf[4];
#pragma unroll
      for (int mb = 0; mb < 4; ++mb)
        af[mb] = *(const half8*)&Xs[wm + mb * 16 + n16][kc * 32 + quad * 8];
#pragma unroll
      for (int nb = 0; nb < 4; ++nb)
        bf[nb] = *(const half8*)&Ws[wn + nb * 16 + n16][kc * 32 + quad * 8];
#pragma unroll
      for (int mb = 0; mb < 4; ++mb)
#pragma unroll
        for (int nb = 0; nb < 4; ++nb)
          acc[mb][nb] = MFMA16(af[mb], bf[nb], acc[mb][nb]);
    }
    __syncthreads();
  }

#pragma unroll
  for (int mb = 0; mb < 4; ++mb)
#pragma unroll
    for (int nb = 0; nb < 4; ++nb)
#pragma unroll
      for (int r = 0; r < 4; ++r) {
        int row = row0 + wm + mb * 16 + quad * 4 + r;
        int col = col0 + wn + nb * 16 + n16;
        Y[(size_t)row * 512 + col] = acc[mb][nb][r] + bias[col];
      }
}

// ---------------------------------------------------------------------------
extern "C" void kernel_launch(void* const* d_in, const int* in_sizes, int n_in,
                              void* d_out, int out_size, void* d_ws, size_t ws_size,
                              hipStream_t stream) {
  const float* x   = (const float*)d_in[0];
  const float* enc = (const float*)d_in[1];
  const float* Wq  = (const float*)d_in[2];
  const float* Wk  = (const float*)d_in[3];
  const float* Wv  = (const float*)d_in[4];
  const float* bq  = (const float*)d_in[5];
  const float* bk  = (const float*)d_in[6];
  const float* bv  = (const float*)d_in[7];
  const float* Wo  = (const float*)d_in[8];
  const float* bo  = (const float*)d_in[9];
  float* out = (float*)d_out;

  // workspace layout (MB offsets):
  //   0  Qh    f16 [4096 x 512]         4 MB
  //   4  Kh    f16 [16384 x 512]       16 MB
  //  20  Vtg   f16 [2048 x 4096]       16 MB
  //  36  Opart f16 [64 x 1024 x 128]   16 MB
  //  52  CTXh  f16 [4096 x 512]         4 MB
  //  56  ml    f32 [64 x 1024 x 2]     0.5 MB
  //  57  Wh    f16 [4 x 512 x 512]      2 MB     (total 59 MB)
  char* ws = (char*)d_ws;
  _Float16* Qh    = (_Float16*)(ws);
  _Float16* Kh    = (_Float16*)(ws + (4u  << 20));
  _Float16* Vtg   = (_Float16*)(ws + (20u << 20));
  _Float16* Opart = (_Float16*)(ws + (36u << 20));
  _Float16* CTXh  = (_Float16*)(ws + (52u << 20));
  float*    mlp   = (float*)   (ws + (56u << 20));
  _Float16* Wh    = (_Float16*)(ws + (57u << 20));

  _Float16* Whq = Wh;
  _Float16* Whk = Wh + 262144;
  _Float16* Whv = Wh + 524288;
  _Float16* Who = Wh + 786432;

  const float qscale = 0.08838834764831845f;  // 1/sqrt(128)
  dim3 blk(256);

  prep_w<<<dim3(1024), blk, 0, stream>>>(Wq, Wk, Wv, Wo, Wh);

  proj_qkv<<<dim3(160, 4), blk, 0, stream>>>(
      x, enc, Whq, Whk, Whv, bq, bk, bv, Qh, Kh, Vtg, qscale);

  flash_mfma2<<<dim3(64, 8), blk, 0, stream>>>(Qh, Kh, Vtg, Opart, mlp);

  combine_splits<<<dim3(8192), blk, 0, stream>>>(Opart, mlp, CTXh);

  proj_out<<<dim3(32, 4), blk, 0, stream>>>(CTXh, Who, bo, out);
}